// Round 1
// baseline (363.366 us; speedup 1.0000x reference)
//
#include <hip/hip_runtime.h>
#include <math.h>

#define B    256
#define NIN  1152
#define IND  8
#define NOUT 10
#define OUTD 16
#define M    160          // NOUT*OUTD
#define K    9216         // NIN*IND

// ---------------- kernel 1: s0 = 0.1 * (u_flat @ W_flat), split-K ----------------
#define BT0 16
#define KS0 32
#define KC0 (K / KS0)     // 288

__global__ void k_s0(const float* __restrict__ u, const float* __restrict__ W,
                     float* __restrict__ spart) {
    __shared__ __align__(16) float u_lds[BT0][KC0];   // 18 KB
    const int m  = threadIdx.x;            // 0..159 (column of W_flat)
    const int b0 = blockIdx.x * BT0;
    const int k0 = blockIdx.y * KC0;
    for (int f = threadIdx.x; f < BT0 * KC0; f += 160) {
        int bb = f / KC0, kk = f % KC0;
        u_lds[bb][kk] = u[(size_t)(b0 + bb) * K + k0 + kk];
    }
    __syncthreads();
    float acc[BT0];
#pragma unroll
    for (int b = 0; b < BT0; ++b) acc[b] = 0.f;
    for (int k = 0; k < KC0; ++k) {
        float w = W[(size_t)(k0 + k) * M + m];
#pragma unroll
        for (int b = 0; b < BT0; ++b) acc[b] += u_lds[b][k] * w;
    }
    float* out = spart + (size_t)blockIdx.y * B * M;
#pragma unroll
    for (int b = 0; b < BT0; ++b) out[(size_t)(b0 + b) * M + m] = 0.1f * acc[b];
}

// ---------------- squash: reduce split-K partials, v = s*|s|/(1+|s|^2) ----------------
__global__ void k_squash(const float* __restrict__ spart, int NS,
                         float* __restrict__ dst) {
    const int m = threadIdx.x;   // 0..159, m = o*16 + d
    const int b = blockIdx.x;
    float s = 0.f;
    for (int ns = 0; ns < NS; ++ns)
        s += spart[(size_t)ns * B * M + (size_t)b * M + m];
    float ss = s * s;
    ss += __shfl_xor(ss, 1);
    ss += __shfl_xor(ss, 2);
    ss += __shfl_xor(ss, 4);
    ss += __shfl_xor(ss, 8);     // sum over the 16 d-lanes of this o-group
    float norm = sqrtf(ss);
    dst[(size_t)b * M + m] = s * norm / (1.f + ss);
}

// ---------------- a-kernel: a[b,n,o] = sum_i u * (sum_d W*v); b+=a; c=softmax ----------------
#define NT  8      // n per block
#define BTA 64     // b per block
template <bool FIRST>
__global__ void k_a(const float* __restrict__ u, const float* __restrict__ W,
                    const float* __restrict__ v, float* __restrict__ blog,
                    float* __restrict__ cbuf) {
    __shared__ __align__(16) float W_lds[NT * IND * M];   // 40 KB, contiguous copy
    __shared__ float v_lds[BTA][161];                     // +1 pad -> conflict-free
    const int n0 = blockIdx.x * NT;
    const int b0 = blockIdx.y * BTA;
    const float* Wsrc = W + (size_t)n0 * IND * M;
    for (int f = threadIdx.x; f < NT * IND * M; f += 512) W_lds[f] = Wsrc[f];
    for (int f = threadIdx.x; f < BTA * M; f += 512) {
        int bb = f / M, mm = f % M;
        v_lds[bb][mm] = v[(size_t)(b0 + bb) * M + mm];
    }
    __syncthreads();
    const int bb = threadIdx.x & 63;   // lane = local batch
    const int ng = threadIdx.x >> 6;   // wave  = local n (wave-uniform)
    const int n  = n0 + ng;
    const int gb = b0 + bb;

    float uu[IND];
    const float* up = u + (size_t)gb * K + (size_t)n * IND;
#pragma unroll
    for (int i = 0; i < IND; ++i) uu[i] = up[i];

    const float* Wn = W_lds + ng * IND * M;
    float a[NOUT];
#pragma unroll
    for (int o = 0; o < NOUT; ++o) {
        float vv[OUTD];
#pragma unroll
        for (int d = 0; d < OUTD; ++d) vv[d] = v_lds[bb][o * OUTD + d];
        float acc = 0.f;
#pragma unroll
        for (int i = 0; i < IND; ++i) {
            const float4* w4 = (const float4*)(Wn + i * M + o * OUTD);
            float wv = 0.f;
#pragma unroll
            for (int q = 0; q < 4; ++q) {
                float4 w = w4[q];
                wv += w.x * vv[q * 4 + 0] + w.y * vv[q * 4 + 1] +
                      w.z * vv[q * 4 + 2] + w.w * vv[q * 4 + 3];
            }
            acc += uu[i] * wv;
        }
        a[o] = acc;
    }

    float bl[NOUT];
    float* bp = blog + ((size_t)n * B + gb) * NOUT;
    if (FIRST) {
#pragma unroll
        for (int o = 0; o < NOUT; ++o) { bl[o] = a[o]; bp[o] = a[o]; }
    } else {
#pragma unroll
        for (int o = 0; o < NOUT; ++o) bl[o] = bp[o] + a[o];
    }
    float mx = bl[0];
#pragma unroll
    for (int o = 1; o < NOUT; ++o) mx = fmaxf(mx, bl[o]);
    float e[NOUT], sum = 0.f;
#pragma unroll
    for (int o = 0; o < NOUT; ++o) { e[o] = __expf(bl[o] - mx); sum += e[o]; }
    float inv = 1.f / sum;
#pragma unroll
    for (int o = 0; o < NOUT; ++o)
        cbuf[((size_t)o * NIN + n) * B + gb] = e[o] * inv;   // coalesced over lanes
}

// ---------------- s-kernel: s[b,o,:] = sum_n c[o,n,b] * (u[b,n,:] @ W[n,:,o,:]) ----------------
#define BTS 16
#define NSP 8
#define NCH (NIN / NSP)   // 144

__global__ void k_s(const float* __restrict__ u, const float* __restrict__ W,
                    const float* __restrict__ cbuf, float* __restrict__ spart) {
    const int o  = blockIdx.x;        // 0..9
    const int bt = blockIdx.y;        // 0..15
    const int ns = blockIdx.z;        // 0..7
    const int dd = threadIdx.x & 15;
    const int bb = threadIdx.x >> 4;  // 0..15
    const int b  = bt * BTS + bb;
    const int n0 = ns * NCH;
    float acc = 0.f;
    const float* up = u + (size_t)b * K;
    for (int nn = 0; nn < NCH; ++nn) {
        int n = n0 + nn;
        float cu = cbuf[((size_t)o * NIN + n) * B + b];
        const float* Wp = W + (size_t)n * IND * M + o * OUTD + dd;
        const float* uq = up + n * IND;
        float uh = 0.f;
#pragma unroll
        for (int i = 0; i < IND; ++i) uh += uq[i] * Wp[i * M];
        acc += cu * uh;
    }
    spart[(size_t)ns * B * M + (size_t)b * M + o * OUTD + dd] = acc;
}

// ---------------- launch ----------------
extern "C" void kernel_launch(void* const* d_in, const int* in_sizes, int n_in,
                              void* d_out, int out_size, void* d_ws, size_t ws_size,
                              hipStream_t stream) {
    const float* u = (const float*)d_in[0];   // [256,1152,8]
    const float* W = (const float*)d_in[1];   // [1152,8,160]
    float* out = (float*)d_out;               // [256,10,16] f32

    float* ws    = (float*)d_ws;
    float* spart = ws;                                    // KS0*B*M   = 1,310,720 f
    float* blog  = spart + (size_t)KS0 * B * M;           // NIN*B*NOUT = 2,949,120 f
    float* cbuf  = blog + (size_t)NIN * B * NOUT;         // NOUT*NIN*B = 2,949,120 f
    float* vbuf  = cbuf + (size_t)NOUT * NIN * B;         // B*M        = 40,960 f
    // total ~29.6 MB of ws

    // iter 0: c uniform (0.1 folded into k_s0)
    k_s0<<<dim3(B / BT0, KS0), 160, 0, stream>>>(u, W, spart);
    k_squash<<<B, 160, 0, stream>>>(spart, KS0, vbuf);
    // a0 -> b1 (=a0), c1
    k_a<true><<<dim3(NIN / NT, B / BTA), 512, 0, stream>>>(u, W, vbuf, blog, cbuf);
    // s1 -> v1
    k_s<<<dim3(NOUT, B / BTS, NSP), 256, 0, stream>>>(u, W, cbuf, spart);
    k_squash<<<B, 160, 0, stream>>>(spart, NSP, vbuf);
    // a1 -> b2 (in-register), c2
    k_a<false><<<dim3(NIN / NT, B / BTA), 512, 0, stream>>>(u, W, vbuf, blog, cbuf);
    // s2 -> v2 = output
    k_s<<<dim3(NOUT, B / BTS, NSP), 256, 0, stream>>>(u, W, cbuf, spart);
    k_squash<<<B, 160, 0, stream>>>(spart, NSP, out);
}

// Round 3
// 234.569 us; speedup vs baseline: 1.5491x; 1.5491x over previous
//
#include <hip/hip_runtime.h>
#include <math.h>

#define B    256
#define NIN  1152
#define IND  8
#define NOUT 10
#define OUTD 16
#define M    160          // NOUT*OUTD
#define K    9216         // NIN*IND

// ================= k_su: s partials over n-chunks ==================
// grid (CHUNKS, B/BTS), 640 threads: thread = (b-local = tid/20, m-tile = tid%20)
// Each thread: 1 batch, 8 output columns (one o), loop 36 n.
#define CHUNKS 32
#define NTOT   (NIN / CHUNKS)   // 36
#define BTS    32

template <int MODE>   // 0: c = 0.1 uniform (iter 0); 1: read cbuf
__global__ __launch_bounds__(640) void k_su(const float* __restrict__ u,
                                            const float* __restrict__ W,
                                            const float* __restrict__ cbuf,
                                            float* __restrict__ spart) {
    const int mt = threadIdx.x % 20;       // m-tile: columns mt*8 .. mt*8+7
    const int bl = threadIdx.x / 20;       // 0..31
    const int o  = mt >> 1;                // output capsule of this m-tile
    const int b  = blockIdx.y * BTS + bl;
    const int n0 = blockIdx.x * NTOT;

    float acc[8];
#pragma unroll
    for (int j = 0; j < 8; ++j) acc[j] = 0.f;

    const float* up = u + (size_t)b * K + (size_t)n0 * IND;
    const float* Wp = W + (size_t)n0 * IND * M + mt * 8;
    const float* cp = MODE ? (cbuf + (size_t)o * NIN * B + (size_t)n0 * B + b) : nullptr;

#pragma unroll 2
    for (int n = 0; n < NTOT; ++n) {
        const float4 u0 = *(const float4*)(up + n * IND);
        const float4 u1 = *(const float4*)(up + n * IND + 4);
        float c = MODE ? cp[(size_t)n * B] : 0.1f;
        float cu[8];
        cu[0] = c * u0.x; cu[1] = c * u0.y; cu[2] = c * u0.z; cu[3] = c * u0.w;
        cu[4] = c * u1.x; cu[5] = c * u1.y; cu[6] = c * u1.z; cu[7] = c * u1.w;
#pragma unroll
        for (int i = 0; i < IND; ++i) {
            const float* wr = Wp + (size_t)(n * IND + i) * M;
            const float4 w0 = *(const float4*)(wr);
            const float4 w1 = *(const float4*)(wr + 4);
            const float cui = cu[i];
            acc[0] = fmaf(cui, w0.x, acc[0]);
            acc[1] = fmaf(cui, w0.y, acc[1]);
            acc[2] = fmaf(cui, w0.z, acc[2]);
            acc[3] = fmaf(cui, w0.w, acc[3]);
            acc[4] = fmaf(cui, w1.x, acc[4]);
            acc[5] = fmaf(cui, w1.y, acc[5]);
            acc[6] = fmaf(cui, w1.z, acc[6]);
            acc[7] = fmaf(cui, w1.w, acc[7]);
        }
    }
    float* sp = spart + (size_t)blockIdx.x * B * M + (size_t)b * M + mt * 8;
    *(float4*)(sp)     = make_float4(acc[0], acc[1], acc[2], acc[3]);
    *(float4*)(sp + 4) = make_float4(acc[4], acc[5], acc[6], acc[7]);
}

// ================= k_squash: reduce 32 partials + squash ==================
// grid 640 x 64, thread per output element (b,m). TRANS=1 -> write v transposed [M][B].
template <int TRANS>
__global__ __launch_bounds__(64) void k_squash(const float* __restrict__ spart,
                                               float* __restrict__ dst) {
    const int gid = blockIdx.x * 64 + threadIdx.x;   // 0..40959
    float s = 0.f;
#pragma unroll
    for (int ch = 0; ch < CHUNKS; ++ch) s += spart[(size_t)ch * B * M + gid];
    float ss = s * s;
    ss += __shfl_xor(ss, 1);
    ss += __shfl_xor(ss, 2);
    ss += __shfl_xor(ss, 4);
    ss += __shfl_xor(ss, 8);          // sum over the 16 d-lanes (160 % 16 == 0)
    const float v = s * sqrtf(ss) / (1.f + ss);
    if (TRANS) {
        const int b = gid / M, m = gid % M;
        dst[(size_t)m * B + b] = v;
    } else {
        dst[gid] = v;
    }
}

// ================= k_a: a = uhat . v ; b += a ; c = softmax(b) ==================
// grid (NIN/NA, B/64), 576 threads: lane = batch, wave = n. No LDS.
// W addresses are wave-uniform -> scalar loads; v read from transposed vt [M][B].
#define NA 9

template <int FIRST>
__global__ __launch_bounds__(576) void k_a(const float* __restrict__ u,
                                           const float* __restrict__ W,
                                           const float* __restrict__ vt,
                                           float* __restrict__ blog,
                                           float* __restrict__ cbuf) {
    const int bb = threadIdx.x & 63;
    const int ng = threadIdx.x >> 6;            // 0..8, wave-uniform
    const int n  = blockIdx.x * NA + ng;
    const int gb = blockIdx.y * 64 + bb;

    float uu[IND];
    {
        const float4 u0 = *(const float4*)(u + (size_t)gb * K + (size_t)n * IND);
        const float4 u1 = *(const float4*)(u + (size_t)gb * K + (size_t)n * IND + 4);
        uu[0] = u0.x; uu[1] = u0.y; uu[2] = u0.z; uu[3] = u0.w;
        uu[4] = u1.x; uu[5] = u1.y; uu[6] = u1.z; uu[7] = u1.w;
    }
    const int nbase = __builtin_amdgcn_readfirstlane(n * (IND * M));
    const float* vcol = vt + gb;

    float a[NOUT];
#pragma unroll
    for (int o = 0; o < NOUT; ++o) {
        float vv[OUTD];
#pragma unroll
        for (int d = 0; d < OUTD; ++d) vv[d] = vcol[(size_t)(o * OUTD + d) * B];
        const float* wb = W + nbase + o * OUTD;
        float acc = 0.f;
#pragma unroll
        for (int i = 0; i < IND; ++i) {
            const float* wr = wb + i * M;      // wave-uniform address
            float wv = 0.f;
#pragma unroll
            for (int d = 0; d < OUTD; ++d) wv = fmaf(wr[d], vv[d], wv);
            acc = fmaf(uu[i], wv, acc);
        }
        a[o] = acc;
    }

    float bl[NOUT];
    if (FIRST) {
        float* bp = blog + ((size_t)n * B + gb) * NOUT;
#pragma unroll
        for (int o = 0; o < NOUT; ++o) { bl[o] = a[o]; bp[o] = a[o]; }
    } else {
        const float* bp = blog + ((size_t)n * B + gb) * NOUT;
#pragma unroll
        for (int o = 0; o < NOUT; ++o) bl[o] = bp[o] + a[o];
    }
    float mx = bl[0];
#pragma unroll
    for (int o = 1; o < NOUT; ++o) mx = fmaxf(mx, bl[o]);
    float e[NOUT], sum = 0.f;
#pragma unroll
    for (int o = 0; o < NOUT; ++o) { e[o] = __expf(bl[o] - mx); sum += e[o]; }
    const float inv = 1.f / sum;
#pragma unroll
    for (int o = 0; o < NOUT; ++o)
        cbuf[((size_t)o * NIN + n) * B + gb] = e[o] * inv;
}

// ================= launch ==================
extern "C" void kernel_launch(void* const* d_in, const int* in_sizes, int n_in,
                              void* d_out, int out_size, void* d_ws, size_t ws_size,
                              hipStream_t stream) {
    const float* u = (const float*)d_in[0];   // [256,1152,8]
    const float* W = (const float*)d_in[1];   // [1152,8,160]
    float* out = (float*)d_out;               // [256,10,16] f32

    float* ws    = (float*)d_ws;
    float* spart = ws;                                   // CHUNKS*B*M  = 1,310,720 f
    float* vt    = spart + (size_t)CHUNKS * B * M;       // M*B         =    40,960 f
    float* blog  = vt + (size_t)M * B;                   // NIN*B*NOUT  = 2,949,120 f
    float* cbuf  = blog + (size_t)NIN * B * NOUT;        // NOUT*NIN*B  = 2,949,120 f
    // total ~29.0 MB

    const dim3 gs(CHUNKS, B / BTS);          // (32, 8)
    const dim3 ga(NIN / NA, B / 64);         // (128, 4)

    // iter 0: uniform c = 0.1
    k_su<0><<<gs, 640, 0, stream>>>(u, W, cbuf, spart);
    k_squash<1><<<640, 64, 0, stream>>>(spart, vt);
    // a0 -> blog=b1, c1
    k_a<1><<<ga, 576, 0, stream>>>(u, W, vt, blog, cbuf);
    // s1 -> v1
    k_su<1><<<gs, 640, 0, stream>>>(u, W, cbuf, spart);
    k_squash<1><<<640, 64, 0, stream>>>(spart, vt);
    // a1 -> b2 (in-register), c2
    k_a<0><<<ga, 576, 0, stream>>>(u, W, vt, blog, cbuf);
    // s2 -> v2 = output
    k_su<1><<<gs, 640, 0, stream>>>(u, W, cbuf, spart);
    k_squash<0><<<640, 64, 0, stream>>>(spart, out);
}